// Round 9
// baseline (748.997 us; speedup 1.0000x reference)
//
#include <hip/hip_runtime.h>
#include <cstdint>

typedef _Float16 f16x8 __attribute__((ext_vector_type(8)));
typedef float f32x4 __attribute__((ext_vector_type(4)));

typedef __attribute__((address_space(1))) void gvoid;
typedef __attribute__((address_space(3))) void lvoid;

__device__ __forceinline__ void gload16(const void* g, void* l) {
    __builtin_amdgcn_global_load_lds((gvoid*)g, (lvoid*)l, 16, 0, 0);
}

// ---------------------------------------------------------------------------
// Downsample f,b (::2,::2) into compact fp32 planes ds[bb][c][a][v].
__global__ __launch_bounds__(256) void downsample_kernel(const float* __restrict__ f,
                                                         const float* __restrict__ b,
                                                         float* __restrict__ fds,
                                                         float* __restrict__ bds) {
    int idx = blockIdx.x * 256 + threadIdx.x;
    const float* src = blockIdx.y ? b : f;
    float* dst = blockIdx.y ? bds : fds;
    int bb = idx >> 19;
    int r = idx & 524287;
    int c = r >> 12, a = (r >> 6) & 63, v = r & 63;
    dst[idx] = src[(size_t)bb * 2097152 + (size_t)c * 16384 + (2 * a) * 128 + 2 * v];
}

// ---------------------------------------------------------------------------
__global__ __launch_bounds__(256) void build_mm_kernel(const float* __restrict__ mask,
                                                       float* __restrict__ mm) {
    int l = blockIdx.x * 256 + threadIdx.x;
    if (l >= 4096) return;
    int i = l >> 6, j = l & 63;
    float s = 0.f;
    #pragma unroll
    for (int dy = 0; dy < 3; ++dy)
        #pragma unroll
        for (int dx = 0; dx < 3; ++dx) {
            int a = i + dy - 1, b = j + dx - 1;
            if ((unsigned)a < 64u && (unsigned)b < 64u)
                s += mask[(2 * a) * 128 + 2 * b];
        }
    mm[l] = (s == 0.0f) ? 1.0f : 0.0f;
}

// ---------------------------------------------------------------------------
// Both batches: grid 8192. K-order k = c*9 + s. Reads L2-hot f_ds.
__global__ __launch_bounds__(256) void build_fpatch_kernel(const float* __restrict__ fds,
                                                           _Float16* __restrict__ Fp) {
    int bb = blockIdx.x >> 12;
    int p = blockIdx.x & 4095;
    const float* fb = fds + (size_t)bb * 524288;
    _Float16* Fpb = Fp + (size_t)bb * 4718592;
    int u = p >> 6, v = p & 63;
    for (int k = threadIdx.x; k < 1152; k += 256) {
        int c = k / 9;
        int s = k - 9 * c;
        int dy = s / 3, dx = s - 3 * dy;
        int a = u + dy - 1, bcol = v + dx - 1;
        float val = 0.f;
        if ((unsigned)a < 64u && (unsigned)bcol < 64u)
            val = fb[c * 4096 + a * 64 + bcol];
        Fpb[(size_t)p * 1152 + k] = (_Float16)val;
    }
}

// ---------------------------------------------------------------------------
__global__ __launch_bounds__(256) void build_wn_kernel(const float* __restrict__ bds,
                                                       _Float16* __restrict__ Wn) {
    __shared__ float wsh[1152];
    __shared__ float red[4];
    int bb = blockIdx.x >> 12;
    int l = blockIdx.x & 4095;
    const float* bp = bds + (size_t)bb * 524288;
    _Float16* Wnb = Wn + (size_t)bb * 4718592;
    int i = l >> 6, j = l & 63;
    float sq = 0.f;
    for (int k = threadIdx.x; k < 1152; k += 256) {
        int c = k / 9;
        int s = k - 9 * c;
        int dy = s / 3, dx = s - 3 * dy;
        int a = i + dy - 1, bcol = j + dx - 1;
        float val = 0.f;
        if ((unsigned)a < 64u && (unsigned)bcol < 64u)
            val = bp[c * 4096 + a * 64 + bcol];
        wsh[k] = val;
        sq += val * val;
    }
    #pragma unroll
    for (int off = 32; off > 0; off >>= 1) sq += __shfl_xor(sq, off);
    if ((threadIdx.x & 63) == 0) red[threadIdx.x >> 6] = sq;
    __syncthreads();
    float total = red[0] + red[1] + red[2] + red[3] + 0.1152f;
    float rinv = 1.0f / sqrtf(total);
    for (int k = threadIdx.x; k < 1152; k += 256)
        Wnb[(size_t)l * 1152 + k] = (_Float16)(wsh[k] * rinv);
}

// ---------------------------------------------------------------------------
__global__ __launch_bounds__(256) void build_vt_kernel(const float* __restrict__ b,
                                                       _Float16* __restrict__ Vt) {
    int bb = blockIdx.x >> 11;
    int n = blockIdx.x & 2047;
    const float* bp = b + (size_t)bb * 2097152;
    _Float16* Vtb = Vt + (size_t)bb * 8388608;
    int c = n >> 4, r = n & 15, rh = r >> 2, rw = r & 3;
    const float* bc = bp + (size_t)c * 16384;
    for (int l = threadIdx.x; l < 4096; l += 256) {
        int lh = l >> 6, lw = l & 63;
        int row = 2 * lh + rh - 1, col = 2 * lw + rw - 1;
        float val = 0.f;
        if ((unsigned)row < 128u && (unsigned)col < 128u)
            val = bc[row * 128 + col];
        Vtb[(size_t)n * 4096 + l] = (_Float16)val;
    }
}

// ---------------------------------------------------------------------------
// GEMM1 batched over z: S[z][4096][4096] f16 = Fp[z] * Wn[z]^T, fp32 accum.
// Output pointers differ per z (S0 aliasing scheme), passed separately.
__global__ __launch_bounds__(256) void gemm1_kernel(const _Float16* __restrict__ Fp,
                                                    const _Float16* __restrict__ Wn,
                                                    _Float16* __restrict__ C0,
                                                    _Float16* __restrict__ C1) {
    __shared__ __align__(16) _Float16 As[128 * 32];
    __shared__ __align__(16) _Float16 Bs[128 * 32];
    const int z = blockIdx.z;
    const _Float16* A = Fp + (size_t)z * 4718592;
    const _Float16* Bt = Wn + (size_t)z * 4718592;
    _Float16* C = z ? C1 : C0;
    const int tid = threadIdx.x;
    const int lane = tid & 63;
    const int wave = tid >> 6;
    const int quad = lane >> 4;
    const int l16 = lane & 15;
    const int bm = blockIdx.y * 128;
    const int bn = blockIdx.x * 128;
    const int waveM = (wave >> 1) * 64;
    const int waveN = (wave & 1) * 64;
    const int K = 1152;

    f32x4 acc[4][4] = {};

    const int rowS = tid >> 2;
    const int colS = (tid & 3) * 8;

    for (int k0 = 0; k0 < K; k0 += 32) {
        #pragma unroll
        for (int i = 0; i < 2; ++i) {
            const _Float16* g = A + (size_t)(bm + i * 64 + rowS) * K + k0 + colS;
            gload16(g, &As[i * 2048 + tid * 8]);
        }
        #pragma unroll
        for (int i = 0; i < 2; ++i) {
            const _Float16* g = Bt + (size_t)(bn + i * 64 + rowS) * K + k0 + colS;
            gload16(g, &Bs[i * 2048 + tid * 8]);
        }
        __syncthreads();
        f16x8 a_frag[4], b_frag[4];
        #pragma unroll
        for (int mi = 0; mi < 4; ++mi)
            a_frag[mi] = *(const f16x8*)&As[(waveM + mi * 16 + l16) * 32 + quad * 8];
        #pragma unroll
        for (int ni = 0; ni < 4; ++ni)
            b_frag[ni] = *(const f16x8*)&Bs[(waveN + ni * 16 + l16) * 32 + quad * 8];
        #pragma unroll
        for (int mi = 0; mi < 4; ++mi)
            #pragma unroll
            for (int ni = 0; ni < 4; ++ni)
                acc[mi][ni] = __builtin_amdgcn_mfma_f32_16x16x32_f16(
                    a_frag[mi], b_frag[ni], acc[mi][ni], 0, 0, 0);
        __syncthreads();
    }

    #pragma unroll
    for (int mi = 0; mi < 4; ++mi)
        #pragma unroll
        for (int ni = 0; ni < 4; ++ni)
            #pragma unroll
            for (int r = 0; r < 4; ++r) {
                int row = bm + waveM + mi * 16 + quad * 4 + r;
                int col = bn + waveN + ni * 16 + l16;
                C[(size_t)row * 4096 + col] = (_Float16)acc[mi][ni][r];
            }
}

// ---------------------------------------------------------------------------
// GEMM2 (batched over z): OTh[z][n][p] f16 = Vt[z][n][K=4096] . att[z][p][K]
__global__ __launch_bounds__(256) void gemm2_kernel(const _Float16* __restrict__ Vt,
                                                    const _Float16* __restrict__ att,
                                                    _Float16* __restrict__ OTh) {
    __shared__ __align__(16) _Float16 As[128 * 32];
    __shared__ __align__(16) _Float16 Bs[128 * 32];
    const int z = blockIdx.z;
    const _Float16* A = Vt + (size_t)z * 8388608;
    const _Float16* Bt = att + (size_t)z * 16777216;
    _Float16* C = OTh + (size_t)z * 8388608;
    const int tid = threadIdx.x;
    const int lane = tid & 63;
    const int wave = tid >> 6;
    const int quad = lane >> 4;
    const int l16 = lane & 15;
    const int bm = blockIdx.y * 128;
    const int bn = blockIdx.x * 128;
    const int waveM = (wave >> 1) * 64;
    const int waveN = (wave & 1) * 64;
    const int K = 4096;

    f32x4 acc[4][4] = {};

    const int rowS = tid >> 2;
    const int colS = (tid & 3) * 8;

    for (int k0 = 0; k0 < K; k0 += 32) {
        #pragma unroll
        for (int i = 0; i < 2; ++i) {
            const _Float16* g = A + (size_t)(bm + i * 64 + rowS) * K + k0 + colS;
            gload16(g, &As[i * 2048 + tid * 8]);
        }
        #pragma unroll
        for (int i = 0; i < 2; ++i) {
            const _Float16* g = Bt + (size_t)(bn + i * 64 + rowS) * K + k0 + colS;
            gload16(g, &Bs[i * 2048 + tid * 8]);
        }
        __syncthreads();
        f16x8 a_frag[4], b_frag[4];
        #pragma unroll
        for (int mi = 0; mi < 4; ++mi)
            a_frag[mi] = *(const f16x8*)&As[(waveM + mi * 16 + l16) * 32 + quad * 8];
        #pragma unroll
        for (int ni = 0; ni < 4; ++ni)
            b_frag[ni] = *(const f16x8*)&Bs[(waveN + ni * 16 + l16) * 32 + quad * 8];
        #pragma unroll
        for (int mi = 0; mi < 4; ++mi)
            #pragma unroll
            for (int ni = 0; ni < 4; ++ni)
                acc[mi][ni] = __builtin_amdgcn_mfma_f32_16x16x32_f16(
                    a_frag[mi], b_frag[ni], acc[mi][ni], 0, 0, 0);
        __syncthreads();
    }

    #pragma unroll
    for (int mi = 0; mi < 4; ++mi)
        #pragma unroll
        for (int ni = 0; ni < 4; ++ni)
            #pragma unroll
            for (int r = 0; r < 4; ++r) {
                int row = bm + waveM + mi * 16 + quad * 4 + r;
                int col = bn + waveN + ni * 16 + l16;
                C[(size_t)row * 4096 + col] = (_Float16)acc[mi][ni][r];
            }
}

// ---------------------------------------------------------------------------
// Fused double 3-tap "fuse" + mask + softmax, 4 consecutive p per block.
// Rows rr = (interior) p + 64*t2 + t1: consecutive p share 7-8 of 9 rows, so
// taps-outer / pi-inner keeps a ~4-row (32KB, L1-sized) working set and halves
// L3 fetches vs 1-p blocks. Per-p tap order (t2 outer, t1 inner) preserved —
// bitwise identical to previous rounds.
__global__ __launch_bounds__(256) void fuse_softmax_kernel(const _Float16* __restrict__ S0,
                                                           const float* __restrict__ mm,
                                                           _Float16* __restrict__ att) {
    __shared__ float red[4];
    const int tid = threadIdx.x;
    const int lane = tid & 63;
    const int wave = tid >> 6;
    const int p0 = blockIdx.x * 4;

    float acc[4][16];
    #pragma unroll
    for (int pi = 0; pi < 4; ++pi)
        #pragma unroll
        for (int k = 0; k < 16; ++k) acc[pi][k] = 0.f;

    float mv[16];
    #pragma unroll
    for (int k = 0; k < 16; ++k) mv[k] = mm[k * 256 + tid];

    #pragma unroll
    for (int t2 = -1; t2 <= 1; ++t2) {
        #pragma unroll
        for (int t1 = -1; t1 <= 1; ++t1) {
            // row pointers per pi (block-uniform)
            const _Float16* rows[4];
            bool valid[4];
            #pragma unroll
            for (int pi = 0; pi < 4; ++pi) {
                int p = p0 + pi;
                int pbase = ((p & 63) << 6) | (p >> 6);
                int b2 = pbase + t2;
                bool ok = (unsigned)b2 < 4096u;
                int pp = ok ? (((b2 & 63) << 6) | (b2 >> 6)) : 0;
                int rr = pp + t1;
                ok = ok && ((unsigned)rr < 4096u);
                valid[pi] = ok;
                rows[pi] = S0 + (size_t)(ok ? rr : 0) * 4096;
            }
            #pragma unroll
            for (int k = 0; k < 16; ++k) {
                int l = k * 256 + tid;
                int i = (k * 256 + wave * 64) >> 6;   // wave-uniform l-row
                int it2 = i + t2;
                int c;
                bool lane_ok;
                if (it2 >= 0 && it2 < 64) {
                    c = l + t2 * 64 + t1;
                    lane_ok = (unsigned)c < 4096u;
                } else if (it2 == 64) {
                    c = lane + 1 + t1;
                    lane_ok = (lane <= 62) && ((unsigned)c < 4096u);
                } else {  // it2 == -1
                    c = 4031 + lane + t1;
                    lane_ok = (lane >= 1) && ((unsigned)c < 4096u);
                }
                if (lane_ok) {
                    #pragma unroll
                    for (int pi = 0; pi < 4; ++pi)
                        if (valid[pi]) acc[pi][k] += (float)rows[pi][c];
                }
            }
        }
    }

    // per-p softmax
    for (int pi = 0; pi < 4; ++pi) {
        float lmax = -1e30f;
        #pragma unroll
        for (int k = 0; k < 16; ++k) {
            float lg = acc[pi][k] * mv[k] * 10.0f;
            acc[pi][k] = lg;
            lmax = fmaxf(lmax, lg);
        }
        #pragma unroll
        for (int off = 32; off > 0; off >>= 1) lmax = fmaxf(lmax, __shfl_xor(lmax, off));
        if (lane == 0) red[wave] = lmax;
        __syncthreads();
        lmax = fmaxf(fmaxf(red[0], red[1]), fmaxf(red[2], red[3]));
        __syncthreads();
        float lsum = 0.f;
        #pragma unroll
        for (int k = 0; k < 16; ++k) {
            float e = __expf(acc[pi][k] - lmax);
            acc[pi][k] = e;
            lsum += e;
        }
        #pragma unroll
        for (int off = 32; off > 0; off >>= 1) lsum += __shfl_xor(lsum, off);
        if (lane == 0) red[wave] = lsum;
        __syncthreads();
        float inv = 1.0f / (red[0] + red[1] + red[2] + red[3]);
        #pragma unroll
        for (int k = 0; k < 16; ++k) {
            int l = k * 256 + tid;
            att[(size_t)(p0 + pi) * 4096 + l] = (_Float16)(acc[pi][k] * inv * mv[k]);
        }
        __syncthreads();
    }
}

// ---------------------------------------------------------------------------
__global__ __launch_bounds__(256) void assemble_kernel(const _Float16* __restrict__ OTh,
                                                       float* __restrict__ out) {
    int idx = blockIdx.x * 256 + threadIdx.x;
    int bb = idx >> 21;
    int w = idx & 2097151;
    const _Float16* OTb = OTh + (size_t)bb * 8388608;
    int x = w & 127, y = (w >> 7) & 127, c = w >> 14;
    int r0 = (y + 1) & 1, s0 = (x + 1) & 1;
    float acc = 0.f;
    #pragma unroll
    for (int a = 0; a < 2; ++a) {
        int rh = r0 + 2 * a;
        int ph = (y + 1 - rh) >> 1;
        if ((unsigned)ph < 64u) {
            #pragma unroll
            for (int bq = 0; bq < 2; ++bq) {
                int rw = s0 + 2 * bq;
                int pw = (x + 1 - rw) >> 1;
                if ((unsigned)pw < 64u)
                    acc += (float)OTb[(size_t)(c * 16 + rh * 4 + rw) * 4096 + ph * 64 + pw];
            }
        }
    }
    out[idx] = 0.25f * acc;
}

// ---------------------------------------------------------------------------
extern "C" void kernel_launch(void* const* d_in, const int* in_sizes, int n_in,
                              void* d_out, int out_size, void* d_ws, size_t ws_size,
                              hipStream_t stream) {
    const float* f = (const float*)d_in[0];
    const float* b = (const float*)d_in[1];
    const float* mask = (const float*)d_in[2];
    float* out = (float*)d_out;
    char* ws = (char*)d_ws;

    // workspace — total 138,428,416 bytes (proven size)
    // phase A: mm | Fp(2x) Wn(2x) | S0(b1) | att(b0) att(b1)
    //   - fds/bds overlay att(b0) head (dead before fuse(b0) writes att(b0))
    //   - S0(b0) overlays att(b1) slot (consumed by fuse(b0) before fuse(b1)
    //     writes att(b1))
    // phase B: mm | Vt(2x) OTh(2x) ... | att(2x)
    float* mm = (float*)ws;
    _Float16* Fp = (_Float16*)(ws + 16384);
    _Float16* Wn = (_Float16*)(ws + 16384 + 18874368);
    _Float16* S0_b1 = (_Float16*)(ws + 16384 + 2 * 18874368);
    _Float16* att = (_Float16*)(ws + 16384 + 2 * 18874368 + 33554432);
    _Float16* S0_b0 = att + 16777216;               // att(b1) slot overlay
    float* fds = (float*)att;                       // 4 MB overlay
    float* bds = (float*)(((char*)att) + 4194304);  // 4 MB overlay
    _Float16* Vt = (_Float16*)(ws + 16384);
    _Float16* OTh = (_Float16*)(ws + 16384 + 33554432);

    downsample_kernel<<<dim3(4096, 2), 256, 0, stream>>>(f, b, fds, bds);
    build_mm_kernel<<<16, 256, 0, stream>>>(mask, mm);
    build_fpatch_kernel<<<8192, 256, 0, stream>>>(fds, Fp);
    build_wn_kernel<<<8192, 256, 0, stream>>>(bds, Wn);

    gemm1_kernel<<<dim3(32, 32, 2), 256, 0, stream>>>(Fp, Wn, S0_b0, S0_b1);
    fuse_softmax_kernel<<<1024, 256, 0, stream>>>(S0_b0, mm, att);             // b0
    fuse_softmax_kernel<<<1024, 256, 0, stream>>>(S0_b1, mm, att + 16777216);  // b1

    build_vt_kernel<<<4096, 256, 0, stream>>>(b, Vt);
    gemm2_kernel<<<dim3(32, 16, 2), 256, 0, stream>>>(Vt, att, OTh);
    assemble_kernel<<<16384, 256, 0, stream>>>(OTh, out);
}

// Round 10
// 553.117 us; speedup vs baseline: 1.3541x; 1.3541x over previous
//
#include <hip/hip_runtime.h>
#include <cstdint>

typedef _Float16 f16x8 __attribute__((ext_vector_type(8)));
typedef float f32x4 __attribute__((ext_vector_type(4)));

typedef __attribute__((address_space(1))) void gvoid;
typedef __attribute__((address_space(3))) void lvoid;

__device__ __forceinline__ void gload16(const void* g, void* l) {
    __builtin_amdgcn_global_load_lds((gvoid*)g, (lvoid*)l, 16, 0, 0);
}

// ---------------------------------------------------------------------------
// Downsample f,b (::2,::2) into compact fp32 planes ds[bb][c][a][v].
__global__ __launch_bounds__(256) void downsample_kernel(const float* __restrict__ f,
                                                         const float* __restrict__ b,
                                                         float* __restrict__ fds,
                                                         float* __restrict__ bds) {
    int idx = blockIdx.x * 256 + threadIdx.x;
    const float* src = blockIdx.y ? b : f;
    float* dst = blockIdx.y ? bds : fds;
    int bb = idx >> 19;
    int r = idx & 524287;
    int c = r >> 12, a = (r >> 6) & 63, v = r & 63;
    dst[idx] = src[(size_t)bb * 2097152 + (size_t)c * 16384 + (2 * a) * 128 + 2 * v];
}

// ---------------------------------------------------------------------------
__global__ __launch_bounds__(256) void build_mm_kernel(const float* __restrict__ mask,
                                                       float* __restrict__ mm) {
    int l = blockIdx.x * 256 + threadIdx.x;
    if (l >= 4096) return;
    int i = l >> 6, j = l & 63;
    float s = 0.f;
    #pragma unroll
    for (int dy = 0; dy < 3; ++dy)
        #pragma unroll
        for (int dx = 0; dx < 3; ++dx) {
            int a = i + dy - 1, b = j + dx - 1;
            if ((unsigned)a < 64u && (unsigned)b < 64u)
                s += mask[(2 * a) * 128 + 2 * b];
        }
    mm[l] = (s == 0.0f) ? 1.0f : 0.0f;
}

// ---------------------------------------------------------------------------
// Both batches: grid 8192. K-order k = c*9 + s. Reads L2-hot f_ds.
__global__ __launch_bounds__(256) void build_fpatch_kernel(const float* __restrict__ fds,
                                                           _Float16* __restrict__ Fp) {
    int bb = blockIdx.x >> 12;
    int p = blockIdx.x & 4095;
    const float* fb = fds + (size_t)bb * 524288;
    _Float16* Fpb = Fp + (size_t)bb * 4718592;
    int u = p >> 6, v = p & 63;
    for (int k = threadIdx.x; k < 1152; k += 256) {
        int c = k / 9;
        int s = k - 9 * c;
        int dy = s / 3, dx = s - 3 * dy;
        int a = u + dy - 1, bcol = v + dx - 1;
        float val = 0.f;
        if ((unsigned)a < 64u && (unsigned)bcol < 64u)
            val = fb[c * 4096 + a * 64 + bcol];
        Fpb[(size_t)p * 1152 + k] = (_Float16)val;
    }
}

// ---------------------------------------------------------------------------
__global__ __launch_bounds__(256) void build_wn_kernel(const float* __restrict__ bds,
                                                       _Float16* __restrict__ Wn) {
    __shared__ float wsh[1152];
    __shared__ float red[4];
    int bb = blockIdx.x >> 12;
    int l = blockIdx.x & 4095;
    const float* bp = bds + (size_t)bb * 524288;
    _Float16* Wnb = Wn + (size_t)bb * 4718592;
    int i = l >> 6, j = l & 63;
    float sq = 0.f;
    for (int k = threadIdx.x; k < 1152; k += 256) {
        int c = k / 9;
        int s = k - 9 * c;
        int dy = s / 3, dx = s - 3 * dy;
        int a = i + dy - 1, bcol = j + dx - 1;
        float val = 0.f;
        if ((unsigned)a < 64u && (unsigned)bcol < 64u)
            val = bp[c * 4096 + a * 64 + bcol];
        wsh[k] = val;
        sq += val * val;
    }
    #pragma unroll
    for (int off = 32; off > 0; off >>= 1) sq += __shfl_xor(sq, off);
    if ((threadIdx.x & 63) == 0) red[threadIdx.x >> 6] = sq;
    __syncthreads();
    float total = red[0] + red[1] + red[2] + red[3] + 0.1152f;
    float rinv = 1.0f / sqrtf(total);
    for (int k = threadIdx.x; k < 1152; k += 256)
        Wnb[(size_t)l * 1152 + k] = (_Float16)(wsh[k] * rinv);
}

// ---------------------------------------------------------------------------
__global__ __launch_bounds__(256) void build_vt_kernel(const float* __restrict__ b,
                                                       _Float16* __restrict__ Vt) {
    int bb = blockIdx.x >> 11;
    int n = blockIdx.x & 2047;
    const float* bp = b + (size_t)bb * 2097152;
    _Float16* Vtb = Vt + (size_t)bb * 8388608;
    int c = n >> 4, r = n & 15, rh = r >> 2, rw = r & 3;
    const float* bc = bp + (size_t)c * 16384;
    for (int l = threadIdx.x; l < 4096; l += 256) {
        int lh = l >> 6, lw = l & 63;
        int row = 2 * lh + rh - 1, col = 2 * lw + rw - 1;
        float val = 0.f;
        if ((unsigned)row < 128u && (unsigned)col < 128u)
            val = bc[row * 128 + col];
        Vtb[(size_t)n * 4096 + l] = (_Float16)val;
    }
}

// ---------------------------------------------------------------------------
// GEMM1 batched over z: S[z][4096][4096] f16 = Fp[z] * Wn[z]^T, fp32 accum.
__global__ __launch_bounds__(256) void gemm1_kernel(const _Float16* __restrict__ Fp,
                                                    const _Float16* __restrict__ Wn,
                                                    _Float16* __restrict__ C0,
                                                    _Float16* __restrict__ C1) {
    __shared__ __align__(16) _Float16 As[128 * 32];
    __shared__ __align__(16) _Float16 Bs[128 * 32];
    const int z = blockIdx.z;
    const _Float16* A = Fp + (size_t)z * 4718592;
    const _Float16* Bt = Wn + (size_t)z * 4718592;
    _Float16* C = z ? C1 : C0;
    const int tid = threadIdx.x;
    const int lane = tid & 63;
    const int wave = tid >> 6;
    const int quad = lane >> 4;
    const int l16 = lane & 15;
    const int bm = blockIdx.y * 128;
    const int bn = blockIdx.x * 128;
    const int waveM = (wave >> 1) * 64;
    const int waveN = (wave & 1) * 64;
    const int K = 1152;

    f32x4 acc[4][4] = {};

    const int rowS = tid >> 2;
    const int colS = (tid & 3) * 8;

    for (int k0 = 0; k0 < K; k0 += 32) {
        #pragma unroll
        for (int i = 0; i < 2; ++i) {
            const _Float16* g = A + (size_t)(bm + i * 64 + rowS) * K + k0 + colS;
            gload16(g, &As[i * 2048 + tid * 8]);
        }
        #pragma unroll
        for (int i = 0; i < 2; ++i) {
            const _Float16* g = Bt + (size_t)(bn + i * 64 + rowS) * K + k0 + colS;
            gload16(g, &Bs[i * 2048 + tid * 8]);
        }
        __syncthreads();
        f16x8 a_frag[4], b_frag[4];
        #pragma unroll
        for (int mi = 0; mi < 4; ++mi)
            a_frag[mi] = *(const f16x8*)&As[(waveM + mi * 16 + l16) * 32 + quad * 8];
        #pragma unroll
        for (int ni = 0; ni < 4; ++ni)
            b_frag[ni] = *(const f16x8*)&Bs[(waveN + ni * 16 + l16) * 32 + quad * 8];
        #pragma unroll
        for (int mi = 0; mi < 4; ++mi)
            #pragma unroll
            for (int ni = 0; ni < 4; ++ni)
                acc[mi][ni] = __builtin_amdgcn_mfma_f32_16x16x32_f16(
                    a_frag[mi], b_frag[ni], acc[mi][ni], 0, 0, 0);
        __syncthreads();
    }

    #pragma unroll
    for (int mi = 0; mi < 4; ++mi)
        #pragma unroll
        for (int ni = 0; ni < 4; ++ni)
            #pragma unroll
            for (int r = 0; r < 4; ++r) {
                int row = bm + waveM + mi * 16 + quad * 4 + r;
                int col = bn + waveN + ni * 16 + l16;
                C[(size_t)row * 4096 + col] = (_Float16)acc[mi][ni][r];
            }
}

// ---------------------------------------------------------------------------
// GEMM2 (batched over z): OTh[z][n][p] f16 = Vt[z][n][K=4096] . att[z][p][K]
__global__ __launch_bounds__(256) void gemm2_kernel(const _Float16* __restrict__ Vt,
                                                    const _Float16* __restrict__ att,
                                                    _Float16* __restrict__ OTh) {
    __shared__ __align__(16) _Float16 As[128 * 32];
    __shared__ __align__(16) _Float16 Bs[128 * 32];
    const int z = blockIdx.z;
    const _Float16* A = Vt + (size_t)z * 8388608;
    const _Float16* Bt = att + (size_t)z * 16777216;
    _Float16* C = OTh + (size_t)z * 8388608;
    const int tid = threadIdx.x;
    const int lane = tid & 63;
    const int wave = tid >> 6;
    const int quad = lane >> 4;
    const int l16 = lane & 15;
    const int bm = blockIdx.y * 128;
    const int bn = blockIdx.x * 128;
    const int waveM = (wave >> 1) * 64;
    const int waveN = (wave & 1) * 64;
    const int K = 4096;

    f32x4 acc[4][4] = {};

    const int rowS = tid >> 2;
    const int colS = (tid & 3) * 8;

    for (int k0 = 0; k0 < K; k0 += 32) {
        #pragma unroll
        for (int i = 0; i < 2; ++i) {
            const _Float16* g = A + (size_t)(bm + i * 64 + rowS) * K + k0 + colS;
            gload16(g, &As[i * 2048 + tid * 8]);
        }
        #pragma unroll
        for (int i = 0; i < 2; ++i) {
            const _Float16* g = Bt + (size_t)(bn + i * 64 + rowS) * K + k0 + colS;
            gload16(g, &Bs[i * 2048 + tid * 8]);
        }
        __syncthreads();
        f16x8 a_frag[4], b_frag[4];
        #pragma unroll
        for (int mi = 0; mi < 4; ++mi)
            a_frag[mi] = *(const f16x8*)&As[(waveM + mi * 16 + l16) * 32 + quad * 8];
        #pragma unroll
        for (int ni = 0; ni < 4; ++ni)
            b_frag[ni] = *(const f16x8*)&Bs[(waveN + ni * 16 + l16) * 32 + quad * 8];
        #pragma unroll
        for (int mi = 0; mi < 4; ++mi)
            #pragma unroll
            for (int ni = 0; ni < 4; ++ni)
                acc[mi][ni] = __builtin_amdgcn_mfma_f32_16x16x32_f16(
                    a_frag[mi], b_frag[ni], acc[mi][ni], 0, 0, 0);
        __syncthreads();
    }

    #pragma unroll
    for (int mi = 0; mi < 4; ++mi)
        #pragma unroll
        for (int ni = 0; ni < 4; ++ni)
            #pragma unroll
            for (int r = 0; r < 4; ++r) {
                int row = bm + waveM + mi * 16 + quad * 4 + r;
                int col = bn + waveN + ni * 16 + l16;
                C[(size_t)row * 4096 + col] = (_Float16)acc[mi][ni][r];
            }
}

// ---------------------------------------------------------------------------
// Fused double 3-tap "fuse" + mask + softmax: R8-proven version (1 p/block,
// 9 shifted coalesced row-reads, 16 fp32 acc regs/thread — stays under the
// register cliff; the 4-p variant spilled and regressed 2x, R9 post-mortem).
__global__ __launch_bounds__(256) void fuse_softmax_kernel(const _Float16* __restrict__ S0,
                                                           const float* __restrict__ mm,
                                                           _Float16* __restrict__ att) {
    __shared__ float red[4];
    const int tid = threadIdx.x;
    const int lane = tid & 63;
    const int wave = tid >> 6;
    const int p = blockIdx.x;
    const int pbase = ((p & 63) << 6) | (p >> 6);  // T(p)

    float acc[16];
    #pragma unroll
    for (int k = 0; k < 16; ++k) acc[k] = 0.f;

    #pragma unroll
    for (int t2 = -1; t2 <= 1; ++t2) {
        int b2 = pbase + t2;
        if ((unsigned)b2 >= 4096u) continue;
        int pp = ((b2 & 63) << 6) | (b2 >> 6);
        #pragma unroll
        for (int t1 = -1; t1 <= 1; ++t1) {
            int rr = pp + t1;
            if ((unsigned)rr >= 4096u) continue;
            const _Float16* row = S0 + (size_t)rr * 4096;
            #pragma unroll
            for (int k = 0; k < 16; ++k) {
                int l = k * 256 + tid;
                int i = (k * 256 + wave * 64) >> 6;
                int it2 = i + t2;
                if (it2 >= 0 && it2 < 64) {
                    int c = l + t2 * 64 + t1;
                    if ((unsigned)c < 4096u)
                        acc[k] += (float)row[c];
                } else if (it2 == 64) {
                    if (lane <= 62) {
                        int c = lane + 1 + t1;
                        if ((unsigned)c < 4096u) acc[k] += (float)row[c];
                    }
                } else {
                    if (lane >= 1) {
                        int c = 4031 + lane + t1;
                        if ((unsigned)c < 4096u) acc[k] += (float)row[c];
                    }
                }
            }
        }
    }

    float mv[16];
    float lmax = -1e30f;
    #pragma unroll
    for (int k = 0; k < 16; ++k) {
        int l = k * 256 + tid;
        mv[k] = mm[l];
        float lg = acc[k] * mv[k] * 10.0f;
        acc[k] = lg;
        lmax = fmaxf(lmax, lg);
    }
    #pragma unroll
    for (int off = 32; off > 0; off >>= 1) lmax = fmaxf(lmax, __shfl_xor(lmax, off));
    if (lane == 0) red[wave] = lmax;
    __syncthreads();
    lmax = fmaxf(fmaxf(red[0], red[1]), fmaxf(red[2], red[3]));
    __syncthreads();

    float lsum = 0.f;
    #pragma unroll
    for (int k = 0; k < 16; ++k) {
        float e = __expf(acc[k] - lmax);
        acc[k] = e;
        lsum += e;
    }
    #pragma unroll
    for (int off = 32; off > 0; off >>= 1) lsum += __shfl_xor(lsum, off);
    if (lane == 0) red[wave] = lsum;
    __syncthreads();
    float inv = 1.0f / (red[0] + red[1] + red[2] + red[3]);
    #pragma unroll
    for (int k = 0; k < 16; ++k) {
        int l = k * 256 + tid;
        att[(size_t)p * 4096 + l] = (_Float16)(acc[k] * inv * mv[k]);
    }
}

// ---------------------------------------------------------------------------
__global__ __launch_bounds__(256) void assemble_kernel(const _Float16* __restrict__ OTh,
                                                       float* __restrict__ out) {
    int idx = blockIdx.x * 256 + threadIdx.x;
    int bb = idx >> 21;
    int w = idx & 2097151;
    const _Float16* OTb = OTh + (size_t)bb * 8388608;
    int x = w & 127, y = (w >> 7) & 127, c = w >> 14;
    int r0 = (y + 1) & 1, s0 = (x + 1) & 1;
    float acc = 0.f;
    #pragma unroll
    for (int a = 0; a < 2; ++a) {
        int rh = r0 + 2 * a;
        int ph = (y + 1 - rh) >> 1;
        if ((unsigned)ph < 64u) {
            #pragma unroll
            for (int bq = 0; bq < 2; ++bq) {
                int rw = s0 + 2 * bq;
                int pw = (x + 1 - rw) >> 1;
                if ((unsigned)pw < 64u)
                    acc += (float)OTb[(size_t)(c * 16 + rh * 4 + rw) * 4096 + ph * 64 + pw];
            }
        }
    }
    out[idx] = 0.25f * acc;
}

// ---------------------------------------------------------------------------
extern "C" void kernel_launch(void* const* d_in, const int* in_sizes, int n_in,
                              void* d_out, int out_size, void* d_ws, size_t ws_size,
                              hipStream_t stream) {
    const float* f = (const float*)d_in[0];
    const float* b = (const float*)d_in[1];
    const float* mask = (const float*)d_in[2];
    float* out = (float*)d_out;
    char* ws = (char*)d_ws;

    // workspace — total 138,428,416 bytes (proven size)
    // phase A: mm | Fp(2x) Wn(2x) | S0(b1) | att(b0) att(b1)
    //   - fds/bds overlay att(b0) head (dead before fuse(b0) writes att(b0))
    //   - S0(b0) overlays att(b1) slot (consumed by fuse(b0) before fuse(b1)
    //     writes att(b1))
    // phase B: mm | Vt(2x) OTh(2x) ... | att(2x)
    float* mm = (float*)ws;
    _Float16* Fp = (_Float16*)(ws + 16384);
    _Float16* Wn = (_Float16*)(ws + 16384 + 18874368);
    _Float16* S0_b1 = (_Float16*)(ws + 16384 + 2 * 18874368);
    _Float16* att = (_Float16*)(ws + 16384 + 2 * 18874368 + 33554432);
    _Float16* S0_b0 = att + 16777216;               // att(b1) slot overlay
    float* fds = (float*)att;                       // 4 MB overlay
    float* bds = (float*)(((char*)att) + 4194304);  // 4 MB overlay
    _Float16* Vt = (_Float16*)(ws + 16384);
    _Float16* OTh = (_Float16*)(ws + 16384 + 33554432);

    downsample_kernel<<<dim3(4096, 2), 256, 0, stream>>>(f, b, fds, bds);
    build_mm_kernel<<<16, 256, 0, stream>>>(mask, mm);
    build_fpatch_kernel<<<8192, 256, 0, stream>>>(fds, Fp);
    build_wn_kernel<<<8192, 256, 0, stream>>>(bds, Wn);

    gemm1_kernel<<<dim3(32, 32, 2), 256, 0, stream>>>(Fp, Wn, S0_b0, S0_b1);
    fuse_softmax_kernel<<<4096, 256, 0, stream>>>(S0_b0, mm, att);             // b0
    fuse_softmax_kernel<<<4096, 256, 0, stream>>>(S0_b1, mm, att + 16777216);  // b1

    build_vt_kernel<<<4096, 256, 0, stream>>>(b, Vt);
    gemm2_kernel<<<dim3(32, 16, 2), 256, 0, stream>>>(Vt, att, OTh);
    assemble_kernel<<<16384, 256, 0, stream>>>(OTh, out);
}

// Round 11
// 487.556 us; speedup vs baseline: 1.5362x; 1.1345x over previous
//
#include <hip/hip_runtime.h>
#include <cstdint>

typedef _Float16 f16x8 __attribute__((ext_vector_type(8)));
typedef float f32x4 __attribute__((ext_vector_type(4)));

typedef __attribute__((address_space(1))) void gvoid;
typedef __attribute__((address_space(3))) void lvoid;

__device__ __forceinline__ void gload16(const void* g, void* l) {
    __builtin_amdgcn_global_load_lds((gvoid*)g, (lvoid*)l, 16, 0, 0);
}

// ---------------------------------------------------------------------------
// Downsample f,b (::2,::2) into compact fp32 planes ds[bb][c][a][v].
__global__ __launch_bounds__(256) void downsample_kernel(const float* __restrict__ f,
                                                         const float* __restrict__ b,
                                                         float* __restrict__ fds,
                                                         float* __restrict__ bds) {
    int idx = blockIdx.x * 256 + threadIdx.x;
    const float* src = blockIdx.y ? b : f;
    float* dst = blockIdx.y ? bds : fds;
    int bb = idx >> 19;
    int r = idx & 524287;
    int c = r >> 12, a = (r >> 6) & 63, v = r & 63;
    dst[idx] = src[(size_t)bb * 2097152 + (size_t)c * 16384 + (2 * a) * 128 + 2 * v];
}

// ---------------------------------------------------------------------------
__global__ __launch_bounds__(256) void build_mm_kernel(const float* __restrict__ mask,
                                                       float* __restrict__ mm) {
    int l = blockIdx.x * 256 + threadIdx.x;
    if (l >= 4096) return;
    int i = l >> 6, j = l & 63;
    float s = 0.f;
    #pragma unroll
    for (int dy = 0; dy < 3; ++dy)
        #pragma unroll
        for (int dx = 0; dx < 3; ++dx) {
            int a = i + dy - 1, b = j + dx - 1;
            if ((unsigned)a < 64u && (unsigned)b < 64u)
                s += mask[(2 * a) * 128 + 2 * b];
        }
    mm[l] = (s == 0.0f) ? 1.0f : 0.0f;
}

// ---------------------------------------------------------------------------
// Both batches: grid 8192. K-order k = c*9 + s. Reads L2-hot f_ds.
__global__ __launch_bounds__(256) void build_fpatch_kernel(const float* __restrict__ fds,
                                                           _Float16* __restrict__ Fp) {
    int bb = blockIdx.x >> 12;
    int p = blockIdx.x & 4095;
    const float* fb = fds + (size_t)bb * 524288;
    _Float16* Fpb = Fp + (size_t)bb * 4718592;
    int u = p >> 6, v = p & 63;
    for (int k = threadIdx.x; k < 1152; k += 256) {
        int c = k / 9;
        int s = k - 9 * c;
        int dy = s / 3, dx = s - 3 * dy;
        int a = u + dy - 1, bcol = v + dx - 1;
        float val = 0.f;
        if ((unsigned)a < 64u && (unsigned)bcol < 64u)
            val = fb[c * 4096 + a * 64 + bcol];
        Fpb[(size_t)p * 1152 + k] = (_Float16)val;
    }
}

// ---------------------------------------------------------------------------
__global__ __launch_bounds__(256) void build_wn_kernel(const float* __restrict__ bds,
                                                       _Float16* __restrict__ Wn) {
    __shared__ float wsh[1152];
    __shared__ float red[4];
    int bb = blockIdx.x >> 12;
    int l = blockIdx.x & 4095;
    const float* bp = bds + (size_t)bb * 524288;
    _Float16* Wnb = Wn + (size_t)bb * 4718592;
    int i = l >> 6, j = l & 63;
    float sq = 0.f;
    for (int k = threadIdx.x; k < 1152; k += 256) {
        int c = k / 9;
        int s = k - 9 * c;
        int dy = s / 3, dx = s - 3 * dy;
        int a = i + dy - 1, bcol = j + dx - 1;
        float val = 0.f;
        if ((unsigned)a < 64u && (unsigned)bcol < 64u)
            val = bp[c * 4096 + a * 64 + bcol];
        wsh[k] = val;
        sq += val * val;
    }
    #pragma unroll
    for (int off = 32; off > 0; off >>= 1) sq += __shfl_xor(sq, off);
    if ((threadIdx.x & 63) == 0) red[threadIdx.x >> 6] = sq;
    __syncthreads();
    float total = red[0] + red[1] + red[2] + red[3] + 0.1152f;
    float rinv = 1.0f / sqrtf(total);
    for (int k = threadIdx.x; k < 1152; k += 256)
        Wnb[(size_t)l * 1152 + k] = (_Float16)(wsh[k] * rinv);
}

// ---------------------------------------------------------------------------
__global__ __launch_bounds__(256) void build_vt_kernel(const float* __restrict__ b,
                                                       _Float16* __restrict__ Vt) {
    int bb = blockIdx.x >> 11;
    int n = blockIdx.x & 2047;
    const float* bp = b + (size_t)bb * 2097152;
    _Float16* Vtb = Vt + (size_t)bb * 8388608;
    int c = n >> 4, r = n & 15, rh = r >> 2, rw = r & 3;
    const float* bc = bp + (size_t)c * 16384;
    for (int l = threadIdx.x; l < 4096; l += 256) {
        int lh = l >> 6, lw = l & 63;
        int row = 2 * lh + rh - 1, col = 2 * lw + rw - 1;
        float val = 0.f;
        if ((unsigned)row < 128u && (unsigned)col < 128u)
            val = bc[row * 128 + col];
        Vtb[(size_t)n * 4096 + l] = (_Float16)val;
    }
}

// ---------------------------------------------------------------------------
// GEMM1 batched over z: S0[z][4096][4096] f16 = Fp[z] * Wn[z]^T, fp32 accum.
// S0 output contiguous across z.
__global__ __launch_bounds__(256) void gemm1_kernel(const _Float16* __restrict__ Fp,
                                                    const _Float16* __restrict__ Wn,
                                                    _Float16* __restrict__ S0) {
    __shared__ __align__(16) _Float16 As[128 * 32];
    __shared__ __align__(16) _Float16 Bs[128 * 32];
    const int z = blockIdx.z;
    const _Float16* A = Fp + (size_t)z * 4718592;
    const _Float16* Bt = Wn + (size_t)z * 4718592;
    _Float16* C = S0 + (size_t)z * 16777216;
    const int tid = threadIdx.x;
    const int lane = tid & 63;
    const int wave = tid >> 6;
    const int quad = lane >> 4;
    const int l16 = lane & 15;
    const int bm = blockIdx.y * 128;
    const int bn = blockIdx.x * 128;
    const int waveM = (wave >> 1) * 64;
    const int waveN = (wave & 1) * 64;
    const int K = 1152;

    f32x4 acc[4][4] = {};

    const int rowS = tid >> 2;
    const int colS = (tid & 3) * 8;

    for (int k0 = 0; k0 < K; k0 += 32) {
        #pragma unroll
        for (int i = 0; i < 2; ++i) {
            const _Float16* g = A + (size_t)(bm + i * 64 + rowS) * K + k0 + colS;
            gload16(g, &As[i * 2048 + tid * 8]);
        }
        #pragma unroll
        for (int i = 0; i < 2; ++i) {
            const _Float16* g = Bt + (size_t)(bn + i * 64 + rowS) * K + k0 + colS;
            gload16(g, &Bs[i * 2048 + tid * 8]);
        }
        __syncthreads();
        f16x8 a_frag[4], b_frag[4];
        #pragma unroll
        for (int mi = 0; mi < 4; ++mi)
            a_frag[mi] = *(const f16x8*)&As[(waveM + mi * 16 + l16) * 32 + quad * 8];
        #pragma unroll
        for (int ni = 0; ni < 4; ++ni)
            b_frag[ni] = *(const f16x8*)&Bs[(waveN + ni * 16 + l16) * 32 + quad * 8];
        #pragma unroll
        for (int mi = 0; mi < 4; ++mi)
            #pragma unroll
            for (int ni = 0; ni < 4; ++ni)
                acc[mi][ni] = __builtin_amdgcn_mfma_f32_16x16x32_f16(
                    a_frag[mi], b_frag[ni], acc[mi][ni], 0, 0, 0);
        __syncthreads();
    }

    #pragma unroll
    for (int mi = 0; mi < 4; ++mi)
        #pragma unroll
        for (int ni = 0; ni < 4; ++ni)
            #pragma unroll
            for (int r = 0; r < 4; ++r) {
                int row = bm + waveM + mi * 16 + quad * 4 + r;
                int col = bn + waveN + ni * 16 + l16;
                C[(size_t)row * 4096 + col] = (_Float16)acc[mi][ni][r];
            }
}

// ---------------------------------------------------------------------------
// GEMM2 (batched over z): OTh[z][n][p] f16 = Vt[z][n][K=4096] . att_z[p][K].
// att for the two batches lives at two non-contiguous pointers.
__global__ __launch_bounds__(256) void gemm2_kernel(const _Float16* __restrict__ Vt,
                                                    const _Float16* __restrict__ att0,
                                                    const _Float16* __restrict__ att1,
                                                    _Float16* __restrict__ OTh) {
    __shared__ __align__(16) _Float16 As[128 * 32];
    __shared__ __align__(16) _Float16 Bs[128 * 32];
    const int z = blockIdx.z;
    const _Float16* A = Vt + (size_t)z * 8388608;
    const _Float16* Bt = z ? att1 : att0;
    _Float16* C = OTh + (size_t)z * 8388608;
    const int tid = threadIdx.x;
    const int lane = tid & 63;
    const int wave = tid >> 6;
    const int quad = lane >> 4;
    const int l16 = lane & 15;
    const int bm = blockIdx.y * 128;
    const int bn = blockIdx.x * 128;
    const int waveM = (wave >> 1) * 64;
    const int waveN = (wave & 1) * 64;
    const int K = 4096;

    f32x4 acc[4][4] = {};

    const int rowS = tid >> 2;
    const int colS = (tid & 3) * 8;

    for (int k0 = 0; k0 < K; k0 += 32) {
        #pragma unroll
        for (int i = 0; i < 2; ++i) {
            const _Float16* g = A + (size_t)(bm + i * 64 + rowS) * K + k0 + colS;
            gload16(g, &As[i * 2048 + tid * 8]);
        }
        #pragma unroll
        for (int i = 0; i < 2; ++i) {
            const _Float16* g = Bt + (size_t)(bn + i * 64 + rowS) * K + k0 + colS;
            gload16(g, &Bs[i * 2048 + tid * 8]);
        }
        __syncthreads();
        f16x8 a_frag[4], b_frag[4];
        #pragma unroll
        for (int mi = 0; mi < 4; ++mi)
            a_frag[mi] = *(const f16x8*)&As[(waveM + mi * 16 + l16) * 32 + quad * 8];
        #pragma unroll
        for (int ni = 0; ni < 4; ++ni)
            b_frag[ni] = *(const f16x8*)&Bs[(waveN + ni * 16 + l16) * 32 + quad * 8];
        #pragma unroll
        for (int mi = 0; mi < 4; ++mi)
            #pragma unroll
            for (int ni = 0; ni < 4; ++ni)
                acc[mi][ni] = __builtin_amdgcn_mfma_f32_16x16x32_f16(
                    a_frag[mi], b_frag[ni], acc[mi][ni], 0, 0, 0);
        __syncthreads();
    }

    #pragma unroll
    for (int mi = 0; mi < 4; ++mi)
        #pragma unroll
        for (int ni = 0; ni < 4; ++ni)
            #pragma unroll
            for (int r = 0; r < 4; ++r) {
                int row = bm + waveM + mi * 16 + quad * 4 + r;
                int col = bn + waveN + ni * 16 + l16;
                C[(size_t)row * 4096 + col] = (_Float16)acc[mi][ni][r];
            }
}

// ---------------------------------------------------------------------------
// Fused double 3-tap "fuse" + mask + softmax: R8-proven per-p body (1 p/block,
// 16 fp32 acc regs — under the register cliff). Both batches in ONE dispatch
// (grid 8192) with an XCD-aware swizzle: assuming round-robin block->XCD
// (blk%8), p_global = (blk&7)*1024 + (blk>>3) gives each XCD a contiguous
// 1024-p range, so the 9-tap sliding row window (~1MB) stays in its 4MB L2
// (perf heuristic only — correctness unaffected if mapping differs).
__global__ __launch_bounds__(256) void fuse_softmax_kernel(const _Float16* __restrict__ S0,
                                                           const float* __restrict__ mm,
                                                           _Float16* __restrict__ att0,
                                                           _Float16* __restrict__ att1) {
    __shared__ float red[4];
    const int tid = threadIdx.x;
    const int lane = tid & 63;
    const int wave = tid >> 6;
    int g = blockIdx.x;
    int p_global = ((g & 7) << 10) | (g >> 3);
    const int bb = p_global >> 12;
    const int p = p_global & 4095;
    const _Float16* S = S0 + (size_t)bb * 16777216;
    _Float16* att = bb ? att1 : att0;
    const int pbase = ((p & 63) << 6) | (p >> 6);  // T(p)

    float acc[16];
    #pragma unroll
    for (int k = 0; k < 16; ++k) acc[k] = 0.f;

    #pragma unroll
    for (int t2 = -1; t2 <= 1; ++t2) {
        int b2 = pbase + t2;
        if ((unsigned)b2 >= 4096u) continue;
        int pp = ((b2 & 63) << 6) | (b2 >> 6);
        #pragma unroll
        for (int t1 = -1; t1 <= 1; ++t1) {
            int rr = pp + t1;
            if ((unsigned)rr >= 4096u) continue;
            const _Float16* row = S + (size_t)rr * 4096;
            #pragma unroll
            for (int k = 0; k < 16; ++k) {
                int l = k * 256 + tid;
                int i = (k * 256 + wave * 64) >> 6;
                int it2 = i + t2;
                if (it2 >= 0 && it2 < 64) {
                    int c = l + t2 * 64 + t1;
                    if ((unsigned)c < 4096u)
                        acc[k] += (float)row[c];
                } else if (it2 == 64) {
                    if (lane <= 62) {
                        int c = lane + 1 + t1;
                        if ((unsigned)c < 4096u) acc[k] += (float)row[c];
                    }
                } else {
                    if (lane >= 1) {
                        int c = 4031 + lane + t1;
                        if ((unsigned)c < 4096u) acc[k] += (float)row[c];
                    }
                }
            }
        }
    }

    float mv[16];
    float lmax = -1e30f;
    #pragma unroll
    for (int k = 0; k < 16; ++k) {
        int l = k * 256 + tid;
        mv[k] = mm[l];
        float lg = acc[k] * mv[k] * 10.0f;
        acc[k] = lg;
        lmax = fmaxf(lmax, lg);
    }
    #pragma unroll
    for (int off = 32; off > 0; off >>= 1) lmax = fmaxf(lmax, __shfl_xor(lmax, off));
    if (lane == 0) red[wave] = lmax;
    __syncthreads();
    lmax = fmaxf(fmaxf(red[0], red[1]), fmaxf(red[2], red[3]));
    __syncthreads();

    float lsum = 0.f;
    #pragma unroll
    for (int k = 0; k < 16; ++k) {
        float e = __expf(acc[k] - lmax);
        acc[k] = e;
        lsum += e;
    }
    #pragma unroll
    for (int off = 32; off > 0; off >>= 1) lsum += __shfl_xor(lsum, off);
    if (lane == 0) red[wave] = lsum;
    __syncthreads();
    float inv = 1.0f / (red[0] + red[1] + red[2] + red[3]);
    #pragma unroll
    for (int k = 0; k < 16; ++k) {
        int l = k * 256 + tid;
        att[(size_t)p * 4096 + l] = (_Float16)(acc[k] * inv * mv[k]);
    }
}

// ---------------------------------------------------------------------------
__global__ __launch_bounds__(256) void assemble_kernel(const _Float16* __restrict__ OTh,
                                                       float* __restrict__ out) {
    int idx = blockIdx.x * 256 + threadIdx.x;
    int bb = idx >> 21;
    int w = idx & 2097151;
    const _Float16* OTb = OTh + (size_t)bb * 8388608;
    int x = w & 127, y = (w >> 7) & 127, c = w >> 14;
    int r0 = (y + 1) & 1, s0 = (x + 1) & 1;
    float acc = 0.f;
    #pragma unroll
    for (int a = 0; a < 2; ++a) {
        int rh = r0 + 2 * a;
        int ph = (y + 1 - rh) >> 1;
        if ((unsigned)ph < 64u) {
            #pragma unroll
            for (int bq = 0; bq < 2; ++bq) {
                int rw = s0 + 2 * bq;
                int pw = (x + 1 - rw) >> 1;
                if ((unsigned)pw < 64u)
                    acc += (float)OTb[(size_t)(c * 16 + rh * 4 + rw) * 4096 + ph * 64 + pw];
            }
        }
    }
    out[idx] = 0.25f * acc;
}

// ---------------------------------------------------------------------------
extern "C" void kernel_launch(void* const* d_in, const int* in_sizes, int n_in,
                              void* d_out, int out_size, void* d_ws, size_t ws_size,
                              hipStream_t stream) {
    const float* f = (const float*)d_in[0];
    const float* b = (const float*)d_in[1];
    const float* mask = (const float*)d_in[2];
    float* out = (float*)d_out;
    char* ws = (char*)d_ws;

    // workspace — total 138,428,416 bytes (proven size)
    //   mm   : ws + 0              (16 KB)
    //   A    : ws + 16384          (37,748,736)  Fp+Wn  -> att0 (33.55M) after gemm1
    //   B    : ws + 37,765,120     (67,108,864)  S0(2x) -> Vt + OTh after fuse
    //   C    : ws + 104,873,984    (33,554,432)  fds/bds (8MB) -> att1
    float* mm = (float*)ws;
    _Float16* Fp = (_Float16*)(ws + 16384);
    _Float16* Wn = (_Float16*)(ws + 16384 + 18874368);
    _Float16* att0 = (_Float16*)(ws + 16384);                 // overlays Fp/Wn (dead)
    _Float16* S0 = (_Float16*)(ws + 37765120);
    _Float16* Vt = (_Float16*)(ws + 37765120);                // overlays S0 b0 (dead)
    _Float16* OTh = (_Float16*)(ws + 37765120 + 33554432);    // overlays S0 b1 (dead)
    float* fds = (float*)(ws + 104873984);
    float* bds = (float*)(ws + 104873984 + 4194304);
    _Float16* att1 = (_Float16*)(ws + 104873984);             // overlays fds/bds (dead)

    downsample_kernel<<<dim3(4096, 2), 256, 0, stream>>>(f, b, fds, bds);
    build_mm_kernel<<<16, 256, 0, stream>>>(mask, mm);
    build_fpatch_kernel<<<8192, 256, 0, stream>>>(fds, Fp);
    build_wn_kernel<<<8192, 256, 0, stream>>>(bds, Wn);

    gemm1_kernel<<<dim3(32, 32, 2), 256, 0, stream>>>(Fp, Wn, S0);
    fuse_softmax_kernel<<<8192, 256, 0, stream>>>(S0, mm, att0, att1);

    build_vt_kernel<<<4096, 256, 0, stream>>>(b, Vt);
    gemm2_kernel<<<dim3(32, 16, 2), 256, 0, stream>>>(Vt, att0, att1, OTh);
    assemble_kernel<<<16384, 256, 0, stream>>>(OTh, out);
}

// Round 12
// 461.047 us; speedup vs baseline: 1.6246x; 1.0575x over previous
//
#include <hip/hip_runtime.h>
#include <cstdint>

typedef _Float16 f16x8 __attribute__((ext_vector_type(8)));
typedef float f32x4 __attribute__((ext_vector_type(4)));

typedef __attribute__((address_space(1))) void gvoid;
typedef __attribute__((address_space(3))) void lvoid;

__device__ __forceinline__ void gload16(const void* g, void* l) {
    __builtin_amdgcn_global_load_lds((gvoid*)g, (lvoid*)l, 16, 0, 0);
}

// ---------------------------------------------------------------------------
// Downsample f,b (::2,::2) into compact fp32 planes ds[bb][c][a][v].
__global__ __launch_bounds__(256) void downsample_kernel(const float* __restrict__ f,
                                                         const float* __restrict__ b,
                                                         float* __restrict__ fds,
                                                         float* __restrict__ bds) {
    int idx = blockIdx.x * 256 + threadIdx.x;
    const float* src = blockIdx.y ? b : f;
    float* dst = blockIdx.y ? bds : fds;
    int bb = idx >> 19;
    int r = idx & 524287;
    int c = r >> 12, a = (r >> 6) & 63, v = r & 63;
    dst[idx] = src[(size_t)bb * 2097152 + (size_t)c * 16384 + (2 * a) * 128 + 2 * v];
}

// ---------------------------------------------------------------------------
__global__ __launch_bounds__(256) void build_mm_kernel(const float* __restrict__ mask,
                                                       float* __restrict__ mm) {
    int l = blockIdx.x * 256 + threadIdx.x;
    if (l >= 4096) return;
    int i = l >> 6, j = l & 63;
    float s = 0.f;
    #pragma unroll
    for (int dy = 0; dy < 3; ++dy)
        #pragma unroll
        for (int dx = 0; dx < 3; ++dx) {
            int a = i + dy - 1, b = j + dx - 1;
            if ((unsigned)a < 64u && (unsigned)b < 64u)
                s += mask[(2 * a) * 128 + 2 * b];
        }
    mm[l] = (s == 0.0f) ? 1.0f : 0.0f;
}

// ---------------------------------------------------------------------------
// Both batches: grid 8192. K-order k = c*9 + s. Reads L2-hot f_ds.
__global__ __launch_bounds__(256) void build_fpatch_kernel(const float* __restrict__ fds,
                                                           _Float16* __restrict__ Fp) {
    int bb = blockIdx.x >> 12;
    int p = blockIdx.x & 4095;
    const float* fb = fds + (size_t)bb * 524288;
    _Float16* Fpb = Fp + (size_t)bb * 4718592;
    int u = p >> 6, v = p & 63;
    for (int k = threadIdx.x; k < 1152; k += 256) {
        int c = k / 9;
        int s = k - 9 * c;
        int dy = s / 3, dx = s - 3 * dy;
        int a = u + dy - 1, bcol = v + dx - 1;
        float val = 0.f;
        if ((unsigned)a < 64u && (unsigned)bcol < 64u)
            val = fb[c * 4096 + a * 64 + bcol];
        Fpb[(size_t)p * 1152 + k] = (_Float16)val;
    }
}

// ---------------------------------------------------------------------------
__global__ __launch_bounds__(256) void build_wn_kernel(const float* __restrict__ bds,
                                                       _Float16* __restrict__ Wn) {
    __shared__ float wsh[1152];
    __shared__ float red[4];
    int bb = blockIdx.x >> 12;
    int l = blockIdx.x & 4095;
    const float* bp = bds + (size_t)bb * 524288;
    _Float16* Wnb = Wn + (size_t)bb * 4718592;
    int i = l >> 6, j = l & 63;
    float sq = 0.f;
    for (int k = threadIdx.x; k < 1152; k += 256) {
        int c = k / 9;
        int s = k - 9 * c;
        int dy = s / 3, dx = s - 3 * dy;
        int a = i + dy - 1, bcol = j + dx - 1;
        float val = 0.f;
        if ((unsigned)a < 64u && (unsigned)bcol < 64u)
            val = bp[c * 4096 + a * 64 + bcol];
        wsh[k] = val;
        sq += val * val;
    }
    #pragma unroll
    for (int off = 32; off > 0; off >>= 1) sq += __shfl_xor(sq, off);
    if ((threadIdx.x & 63) == 0) red[threadIdx.x >> 6] = sq;
    __syncthreads();
    float total = red[0] + red[1] + red[2] + red[3] + 0.1152f;
    float rinv = 1.0f / sqrtf(total);
    for (int k = threadIdx.x; k < 1152; k += 256)
        Wnb[(size_t)l * 1152 + k] = (_Float16)(wsh[k] * rinv);
}

// ---------------------------------------------------------------------------
__global__ __launch_bounds__(256) void build_vt_kernel(const float* __restrict__ b,
                                                       _Float16* __restrict__ Vt) {
    int bb = blockIdx.x >> 11;
    int n = blockIdx.x & 2047;
    const float* bp = b + (size_t)bb * 2097152;
    _Float16* Vtb = Vt + (size_t)bb * 8388608;
    int c = n >> 4, r = n & 15, rh = r >> 2, rw = r & 3;
    const float* bc = bp + (size_t)c * 16384;
    for (int l = threadIdx.x; l < 4096; l += 256) {
        int lh = l >> 6, lw = l & 63;
        int row = 2 * lh + rh - 1, col = 2 * lw + rw - 1;
        float val = 0.f;
        if ((unsigned)row < 128u && (unsigned)col < 128u)
            val = bc[row * 128 + col];
        Vtb[(size_t)n * 4096 + l] = (_Float16)val;
    }
}

// ---------------------------------------------------------------------------
// GEMM1 batched over z: S0[z][4096][4096] f16 = Fp[z] * Wn[z]^T, fp32 accum.
// (m97 structure, BK=32 — unchanged this round for attribution.)
__global__ __launch_bounds__(256) void gemm1_kernel(const _Float16* __restrict__ Fp,
                                                    const _Float16* __restrict__ Wn,
                                                    _Float16* __restrict__ S0) {
    __shared__ __align__(16) _Float16 As[128 * 32];
    __shared__ __align__(16) _Float16 Bs[128 * 32];
    const int z = blockIdx.z;
    const _Float16* A = Fp + (size_t)z * 4718592;
    const _Float16* Bt = Wn + (size_t)z * 4718592;
    _Float16* C = S0 + (size_t)z * 16777216;
    const int tid = threadIdx.x;
    const int lane = tid & 63;
    const int wave = tid >> 6;
    const int quad = lane >> 4;
    const int l16 = lane & 15;
    const int bm = blockIdx.y * 128;
    const int bn = blockIdx.x * 128;
    const int waveM = (wave >> 1) * 64;
    const int waveN = (wave & 1) * 64;
    const int K = 1152;

    f32x4 acc[4][4] = {};

    const int rowS = tid >> 2;
    const int colS = (tid & 3) * 8;

    for (int k0 = 0; k0 < K; k0 += 32) {
        #pragma unroll
        for (int i = 0; i < 2; ++i) {
            const _Float16* g = A + (size_t)(bm + i * 64 + rowS) * K + k0 + colS;
            gload16(g, &As[i * 2048 + tid * 8]);
        }
        #pragma unroll
        for (int i = 0; i < 2; ++i) {
            const _Float16* g = Bt + (size_t)(bn + i * 64 + rowS) * K + k0 + colS;
            gload16(g, &Bs[i * 2048 + tid * 8]);
        }
        __syncthreads();
        f16x8 a_frag[4], b_frag[4];
        #pragma unroll
        for (int mi = 0; mi < 4; ++mi)
            a_frag[mi] = *(const f16x8*)&As[(waveM + mi * 16 + l16) * 32 + quad * 8];
        #pragma unroll
        for (int ni = 0; ni < 4; ++ni)
            b_frag[ni] = *(const f16x8*)&Bs[(waveN + ni * 16 + l16) * 32 + quad * 8];
        #pragma unroll
        for (int mi = 0; mi < 4; ++mi)
            #pragma unroll
            for (int ni = 0; ni < 4; ++ni)
                acc[mi][ni] = __builtin_amdgcn_mfma_f32_16x16x32_f16(
                    a_frag[mi], b_frag[ni], acc[mi][ni], 0, 0, 0);
        __syncthreads();
    }

    #pragma unroll
    for (int mi = 0; mi < 4; ++mi)
        #pragma unroll
        for (int ni = 0; ni < 4; ++ni)
            #pragma unroll
            for (int r = 0; r < 4; ++r) {
                int row = bm + waveM + mi * 16 + quad * 4 + r;
                int col = bn + waveN + ni * 16 + l16;
                C[(size_t)row * 4096 + col] = (_Float16)acc[mi][ni][r];
            }
}

// ---------------------------------------------------------------------------
// GEMM2 restructured: BK=64 (half the barrier drains) + XOR-swizzled LDS.
// Staging: lane (rowS=tid>>3, cb=tid&7) loads source granule cb^(rowS&7) and
// stores to fixed slot [row][cb] (keeps global_load_lds's wave-uniform-base +
// lane*16 contract). Reader fetches granule q at [row][q^(row&7)] -> 16 l16
// lanes spread across all 32 banks at 2 lanes/bank = conflict-free (m136).
// K-chunk order per acc (h=0,1 per iter) identical to BK=32 -> bitwise same.
__global__ __launch_bounds__(256) void gemm2_kernel(const _Float16* __restrict__ Vt,
                                                    const _Float16* __restrict__ att0,
                                                    const _Float16* __restrict__ att1,
                                                    _Float16* __restrict__ OTh) {
    __shared__ __align__(16) _Float16 As[128 * 64];
    __shared__ __align__(16) _Float16 Bs[128 * 64];
    const int z = blockIdx.z;
    const _Float16* A = Vt + (size_t)z * 8388608;
    const _Float16* Bt = z ? att1 : att0;
    _Float16* C = OTh + (size_t)z * 8388608;
    const int tid = threadIdx.x;
    const int lane = tid & 63;
    const int wave = tid >> 6;
    const int quad = lane >> 4;
    const int l16 = lane & 15;
    const int bm = blockIdx.y * 128;
    const int bn = blockIdx.x * 128;
    const int waveM = (wave >> 1) * 64;
    const int waveN = (wave & 1) * 64;
    const int K = 4096;

    f32x4 acc[4][4] = {};

    const int rowS = tid >> 3;                     // 0..31
    const int cbs = ((tid & 7) ^ (rowS & 7)) * 8;  // swizzled source granule

    for (int k0 = 0; k0 < K; k0 += 64) {
        #pragma unroll
        for (int i = 0; i < 4; ++i) {
            const _Float16* g = A + (size_t)(bm + i * 32 + rowS) * K + k0 + cbs;
            gload16(g, &As[i * 2048 + tid * 8]);
        }
        #pragma unroll
        for (int i = 0; i < 4; ++i) {
            const _Float16* g = Bt + (size_t)(bn + i * 32 + rowS) * K + k0 + cbs;
            gload16(g, &Bs[i * 2048 + tid * 8]);
        }
        __syncthreads();
        #pragma unroll
        for (int h = 0; h < 2; ++h) {
            f16x8 a_frag[4], b_frag[4];
            #pragma unroll
            for (int mi = 0; mi < 4; ++mi) {
                int r = waveM + mi * 16 + l16;
                int q = h * 4 + quad;
                a_frag[mi] = *(const f16x8*)&As[r * 64 + ((q ^ (r & 7)) * 8)];
            }
            #pragma unroll
            for (int ni = 0; ni < 4; ++ni) {
                int r = waveN + ni * 16 + l16;
                int q = h * 4 + quad;
                b_frag[ni] = *(const f16x8*)&Bs[r * 64 + ((q ^ (r & 7)) * 8)];
            }
            #pragma unroll
            for (int mi = 0; mi < 4; ++mi)
                #pragma unroll
                for (int ni = 0; ni < 4; ++ni)
                    acc[mi][ni] = __builtin_amdgcn_mfma_f32_16x16x32_f16(
                        a_frag[mi], b_frag[ni], acc[mi][ni], 0, 0, 0);
        }
        __syncthreads();
    }

    #pragma unroll
    for (int mi = 0; mi < 4; ++mi)
        #pragma unroll
        for (int ni = 0; ni < 4; ++ni)
            #pragma unroll
            for (int r = 0; r < 4; ++r) {
                int row = bm + waveM + mi * 16 + quad * 4 + r;
                int col = bn + waveN + ni * 16 + l16;
                C[(size_t)row * 4096 + col] = (_Float16)acc[mi][ni][r];
            }
}

// ---------------------------------------------------------------------------
// Fused double 3-tap "fuse" + mask + softmax (R8 body, XCD swizzle, both
// batches in one dispatch).
__global__ __launch_bounds__(256) void fuse_softmax_kernel(const _Float16* __restrict__ S0,
                                                           const float* __restrict__ mm,
                                                           _Float16* __restrict__ att0,
                                                           _Float16* __restrict__ att1) {
    __shared__ float red[4];
    const int tid = threadIdx.x;
    const int lane = tid & 63;
    const int wave = tid >> 6;
    int g = blockIdx.x;
    int p_global = ((g & 7) << 10) | (g >> 3);
    const int bb = p_global >> 12;
    const int p = p_global & 4095;
    const _Float16* S = S0 + (size_t)bb * 16777216;
    _Float16* att = bb ? att1 : att0;
    const int pbase = ((p & 63) << 6) | (p >> 6);  // T(p)

    float acc[16];
    #pragma unroll
    for (int k = 0; k < 16; ++k) acc[k] = 0.f;

    #pragma unroll
    for (int t2 = -1; t2 <= 1; ++t2) {
        int b2 = pbase + t2;
        if ((unsigned)b2 >= 4096u) continue;
        int pp = ((b2 & 63) << 6) | (b2 >> 6);
        #pragma unroll
        for (int t1 = -1; t1 <= 1; ++t1) {
            int rr = pp + t1;
            if ((unsigned)rr >= 4096u) continue;
            const _Float16* row = S + (size_t)rr * 4096;
            #pragma unroll
            for (int k = 0; k < 16; ++k) {
                int l = k * 256 + tid;
                int i = (k * 256 + wave * 64) >> 6;
                int it2 = i + t2;
                if (it2 >= 0 && it2 < 64) {
                    int c = l + t2 * 64 + t1;
                    if ((unsigned)c < 4096u)
                        acc[k] += (float)row[c];
                } else if (it2 == 64) {
                    if (lane <= 62) {
                        int c = lane + 1 + t1;
                        if ((unsigned)c < 4096u) acc[k] += (float)row[c];
                    }
                } else {
                    if (lane >= 1) {
                        int c = 4031 + lane + t1;
                        if ((unsigned)c < 4096u) acc[k] += (float)row[c];
                    }
                }
            }
        }
    }

    float mv[16];
    float lmax = -1e30f;
    #pragma unroll
    for (int k = 0; k < 16; ++k) {
        int l = k * 256 + tid;
        mv[k] = mm[l];
        float lg = acc[k] * mv[k] * 10.0f;
        acc[k] = lg;
        lmax = fmaxf(lmax, lg);
    }
    #pragma unroll
    for (int off = 32; off > 0; off >>= 1) lmax = fmaxf(lmax, __shfl_xor(lmax, off));
    if (lane == 0) red[wave] = lmax;
    __syncthreads();
    lmax = fmaxf(fmaxf(red[0], red[1]), fmaxf(red[2], red[3]));
    __syncthreads();

    float lsum = 0.f;
    #pragma unroll
    for (int k = 0; k < 16; ++k) {
        float e = __expf(acc[k] - lmax);
        acc[k] = e;
        lsum += e;
    }
    #pragma unroll
    for (int off = 32; off > 0; off >>= 1) lsum += __shfl_xor(lsum, off);
    if (lane == 0) red[wave] = lsum;
    __syncthreads();
    float inv = 1.0f / (red[0] + red[1] + red[2] + red[3]);
    #pragma unroll
    for (int k = 0; k < 16; ++k) {
        int l = k * 256 + tid;
        att[(size_t)p * 4096 + l] = (_Float16)(acc[k] * inv * mv[k]);
    }
}

// ---------------------------------------------------------------------------
__global__ __launch_bounds__(256) void assemble_kernel(const _Float16* __restrict__ OTh,
                                                       float* __restrict__ out) {
    int idx = blockIdx.x * 256 + threadIdx.x;
    int bb = idx >> 21;
    int w = idx & 2097151;
    const _Float16* OTb = OTh + (size_t)bb * 8388608;
    int x = w & 127, y = (w >> 7) & 127, c = w >> 14;
    int r0 = (y + 1) & 1, s0 = (x + 1) & 1;
    float acc = 0.f;
    #pragma unroll
    for (int a = 0; a < 2; ++a) {
        int rh = r0 + 2 * a;
        int ph = (y + 1 - rh) >> 1;
        if ((unsigned)ph < 64u) {
            #pragma unroll
            for (int bq = 0; bq < 2; ++bq) {
                int rw = s0 + 2 * bq;
                int pw = (x + 1 - rw) >> 1;
                if ((unsigned)pw < 64u)
                    acc += (float)OTb[(size_t)(c * 16 + rh * 4 + rw) * 4096 + ph * 64 + pw];
            }
        }
    }
    out[idx] = 0.25f * acc;
}

// ---------------------------------------------------------------------------
extern "C" void kernel_launch(void* const* d_in, const int* in_sizes, int n_in,
                              void* d_out, int out_size, void* d_ws, size_t ws_size,
                              hipStream_t stream) {
    const float* f = (const float*)d_in[0];
    const float* b = (const float*)d_in[1];
    const float* mask = (const float*)d_in[2];
    float* out = (float*)d_out;
    char* ws = (char*)d_ws;

    // workspace — total 138,428,416 bytes (proven size)
    //   mm   : ws + 0              (16 KB)
    //   A    : ws + 16384          (37,748,736)  Fp+Wn  -> att0 (33.55M) after gemm1
    //   B    : ws + 37,765,120     (67,108,864)  S0(2x) -> Vt + OTh after fuse
    //   C    : ws + 104,873,984    (33,554,432)  fds/bds (8MB) -> att1
    float* mm = (float*)ws;
    _Float16* Fp = (_Float16*)(ws + 16384);
    _Float16* Wn = (_Float16*)(ws + 16384 + 18874368);
    _Float16* att0 = (_Float16*)(ws + 16384);                 // overlays Fp/Wn (dead)
    _Float16* S0 = (_Float16*)(ws + 37765120);
    _Float16* Vt = (_Float16*)(ws + 37765120);                // overlays S0 b0 (dead)
    _Float16* OTh = (_Float16*)(ws + 37765120 + 33554432);    // overlays S0 b1 (dead)
    float* fds = (float*)(ws + 104873984);
    float* bds = (float*)(ws + 104873984 + 4194304);
    _Float16* att1 = (_Float16*)(ws + 104873984);             // overlays fds/bds (dead)

    downsample_kernel<<<dim3(4096, 2), 256, 0, stream>>>(f, b, fds, bds);
    build_mm_kernel<<<16, 256, 0, stream>>>(mask, mm);
    build_fpatch_kernel<<<8192, 256, 0, stream>>>(fds, Fp);
    build_wn_kernel<<<8192, 256, 0, stream>>>(bds, Wn);

    gemm1_kernel<<<dim3(32, 32, 2), 256, 0, stream>>>(Fp, Wn, S0);
    fuse_softmax_kernel<<<8192, 256, 0, stream>>>(S0, mm, att0, att1);

    build_vt_kernel<<<4096, 256, 0, stream>>>(b, Vt);
    gemm2_kernel<<<dim3(32, 16, 2), 256, 0, stream>>>(Vt, att0, att1, OTh);
    assemble_kernel<<<16384, 256, 0, stream>>>(OTh, out);
}